// Round 1
// baseline (1380.981 us; speedup 1.0000x reference)
//
#include <hip/hip_runtime.h>

#define E_TOTAL 500000
#define DN 128
#define CIN 384      // 2*DN + D_EDGE
#define DH 512
#define DOUT 128
#define MT 32        // edges per block; 500000 = 32 * 15625 exactly
#define LDA 392      // sA leading dim (bf16 elems): 384 + 8 pad
#define LDH 520      // sH leading dim: 512 + 8 pad

typedef short short8 __attribute__((ext_vector_type(8)));
typedef float f32x4 __attribute__((ext_vector_type(4)));

// fp32 -> bf16 round-to-nearest-even (manual, avoids header ABI differences)
__device__ inline short f2bf(float f) {
    unsigned int u = __float_as_uint(f);
    u = (u + 0x7FFFu + ((u >> 16) & 1u)) >> 16;
    return (short)u;
}

// Prep: W1 [384][512] -> W1T bf16 [512][384]; W2 [512][128] -> W2T bf16 [128][512]
__global__ void prep_weights(const float* __restrict__ w1,
                             const float* __restrict__ w2,
                             short* __restrict__ w1t,
                             short* __restrict__ w2t) {
    int i = blockIdx.x * blockDim.x + threadIdx.x;
    if (i < DH * CIN) {
        int n = i / CIN, k = i - n * CIN;
        w1t[i] = f2bf(w1[k * DH + n]);
    } else {
        int j = i - DH * CIN;
        if (j < DOUT * DH) {
            int n = j / DH, k = j - n * DH;
            w2t[j] = f2bf(w2[k * DOUT + n]);
        }
    }
}

__global__ __launch_bounds__(256, 2) void edge_mlp(
        const float* __restrict__ x,
        const int* __restrict__ ei,       // [2][E]
        const float* __restrict__ ea,
        const float* __restrict__ b1,
        const float* __restrict__ b2,
        const short* __restrict__ w1t,    // bf16 [512][384]
        const short* __restrict__ w2t,    // bf16 [128][512]
        float* __restrict__ out) {
    __shared__ short sA[MT][LDA];
    __shared__ short sH[MT][LDH];
    __shared__ int sIdx[2][MT];

    const int tid = threadIdx.x;
    const int wave = tid >> 6;
    const int lane = tid & 63;
    const int l16 = lane & 15;
    const int quad = lane >> 4;
    const int e0 = blockIdx.x * MT;

    // ---- load edge indices ----
    if (tid < MT)            sIdx[0][tid]      = ei[e0 + tid];
    else if (tid < 2 * MT)   sIdx[1][tid - MT] = ei[E_TOTAL + e0 + (tid - MT)];
    __syncthreads();

    // ---- stage A tile: [MT][384] bf16; 96 (row,seg) units of 128 floats ----
    {
        const int lane32 = tid & 31;
        const int unit0 = tid >> 5;          // 8 groups of 32 threads
        for (int u = unit0; u < 3 * MT; u += 8) {
            int r = u / 3;
            int seg = u - r * 3;
            const float* src;
            if (seg == 0)      src = x + (size_t)sIdx[0][r] * DN;
            else if (seg == 1) src = x + (size_t)sIdx[1][r] * DN;
            else               src = ea + (size_t)(e0 + r) * DN;
            float4 v = reinterpret_cast<const float4*>(src)[lane32];
            short4 p;
            p.x = f2bf(v.x); p.y = f2bf(v.y); p.z = f2bf(v.z); p.w = f2bf(v.w);
            *reinterpret_cast<short4*>(&sA[r][seg * DN + lane32 * 4]) = p;
        }
    }
    __syncthreads();

    // ---- GEMM1: [MT][384] @ W1T -> h [MT][512]; wave w owns N range w*128..+127 ----
    f32x4 acc[2][8] = {};
    {
        const int nbase = wave * 128;
        for (int k = 0; k < CIN; k += 32) {
            short8 a0 = *reinterpret_cast<const short8*>(&sA[l16][k + quad * 8]);
            short8 a1 = *reinterpret_cast<const short8*>(&sA[16 + l16][k + quad * 8]);
#pragma unroll
            for (int nt = 0; nt < 8; nt++) {
                int n = nbase + nt * 16 + l16;
                short8 b = *reinterpret_cast<const short8*>(&w1t[(size_t)n * CIN + k + quad * 8]);
                acc[0][nt] = __builtin_amdgcn_mfma_f32_16x16x32_bf16(a0, b, acc[0][nt], 0, 0, 0);
                acc[1][nt] = __builtin_amdgcn_mfma_f32_16x16x32_bf16(a1, b, acc[1][nt], 0, 0, 0);
            }
        }
        // epilogue: +b1, relu, write bf16 to sH
#pragma unroll
        for (int nt = 0; nt < 8; nt++) {
            int n = nbase + nt * 16 + l16;
            float bias = b1[n];
#pragma unroll
            for (int r = 0; r < 4; r++) {
                int m = quad * 4 + r;
                float v0 = fmaxf(acc[0][nt][r] + bias, 0.0f);
                float v1 = fmaxf(acc[1][nt][r] + bias, 0.0f);
                sH[m][n]      = f2bf(v0);
                sH[16 + m][n] = f2bf(v1);
            }
        }
    }
    __syncthreads();

    // ---- GEMM2: h [MT][512] @ W2T -> out [MT][128]; wave w owns N range w*32..+31 ----
    {
        f32x4 acc2[2][2] = {};
        const int nbase = wave * 32;
        for (int k = 0; k < DH; k += 32) {
            short8 h0 = *reinterpret_cast<const short8*>(&sH[l16][k + quad * 8]);
            short8 h1 = *reinterpret_cast<const short8*>(&sH[16 + l16][k + quad * 8]);
#pragma unroll
            for (int nt = 0; nt < 2; nt++) {
                int n = nbase + nt * 16 + l16;
                short8 b = *reinterpret_cast<const short8*>(&w2t[(size_t)n * DH + k + quad * 8]);
                acc2[0][nt] = __builtin_amdgcn_mfma_f32_16x16x32_bf16(h0, b, acc2[0][nt], 0, 0, 0);
                acc2[1][nt] = __builtin_amdgcn_mfma_f32_16x16x32_bf16(h1, b, acc2[1][nt], 0, 0, 0);
            }
        }
        // epilogue: +b2, fp32 store
#pragma unroll
        for (int nt = 0; nt < 2; nt++) {
            int n = nbase + nt * 16 + l16;
            float bias = b2[n];
#pragma unroll
            for (int r = 0; r < 4; r++) {
                int m = quad * 4 + r;
                out[(size_t)(e0 + m) * DOUT + n]      = acc2[0][nt][r] + bias;
                out[(size_t)(e0 + 16 + m) * DOUT + n] = acc2[1][nt][r] + bias;
            }
        }
    }
}

extern "C" void kernel_launch(void* const* d_in, const int* in_sizes, int n_in,
                              void* d_out, int out_size, void* d_ws, size_t ws_size,
                              hipStream_t stream) {
    const float* x  = (const float*)d_in[0];
    const int*   ei = (const int*)d_in[1];
    const float* ea = (const float*)d_in[2];
    const float* W1 = (const float*)d_in[3];
    const float* b1 = (const float*)d_in[4];
    const float* W2 = (const float*)d_in[5];
    const float* b2 = (const float*)d_in[6];
    float* outp = (float*)d_out;

    short* w1t = (short*)d_ws;                  // 512*384*2 = 384 KB
    short* w2t = w1t + DH * CIN;                // 128*512*2 = 128 KB

    // 512*384 + 128*512 = 262144 elems -> 1024 blocks * 256
    prep_weights<<<1024, 256, 0, stream>>>(W1, W2, w1t, w2t);
    edge_mlp<<<E_TOTAL / MT, 256, 0, stream>>>(x, ei, ea, b1, b2, w1t, w2t, outp);
}

// Round 2
// 975.111 us; speedup vs baseline: 1.4162x; 1.4162x over previous
//
#include <hip/hip_runtime.h>

#define E_TOTAL 500000
#define DN 128
#define CIN 384      // 2*DN + D_EDGE
#define DH 512
#define DOUT 128
#define MT 64        // edges per block; 7813 blocks, last block 32 valid edges
#define NBLK 7813
#define LDA 392      // sA leading dim (bf16): 384 + 8 pad -> rows step 4 banks, 2-way max (free)
#define LDH 520      // sH leading dim (bf16): 512 + 8 pad

typedef short short8 __attribute__((ext_vector_type(8)));
typedef float f32x4 __attribute__((ext_vector_type(4)));

__device__ inline short f2bf(float f) {
    unsigned int u = __float_as_uint(f);
    u = (u + 0x7FFFu + ((u >> 16) & 1u)) >> 16;
    return (short)u;
}

// Coalesced 32x32 LDS tile transpose: W1 [384][512] -> w1t bf16 [512][384],
// W2 [512][128] -> w2t bf16 [128][512]. Grid: 192 + 64 = 256 blocks x 256 thr.
__global__ void prep_weights(const float* __restrict__ w1,
                             const float* __restrict__ w2,
                             short* __restrict__ w1t,
                             short* __restrict__ w2t) {
    __shared__ float t[32][33];
    int b = blockIdx.x;
    const float* src; short* dst; int R, C, tr, tc;
    if (b < 192) { src = w1; dst = w1t; R = 384; C = 512; tr = b >> 4; tc = b & 15; }
    else { b -= 192; src = w2; dst = w2t; R = 512; C = 128; tr = b >> 2; tc = b & 3; }
    int lx = threadIdx.x & 31, ly = threadIdx.x >> 5;   // 32 x 8
#pragma unroll
    for (int p = 0; p < 4; p++) {
        int r = tr * 32 + p * 8 + ly;
        t[p * 8 + ly][lx] = src[(size_t)r * C + tc * 32 + lx];
    }
    __syncthreads();
#pragma unroll
    for (int p = 0; p < 4; p++) {
        int c = tc * 32 + p * 8 + ly;                   // dst row = src col
        dst[(size_t)c * R + tr * 32 + lx] = f2bf(t[lx][p * 8 + ly]);
    }
}

__global__ __launch_bounds__(512, 4) void edge_mlp(
        const float* __restrict__ x,
        const int* __restrict__ ei,       // [2][E]
        const float* __restrict__ ea,
        const float* __restrict__ b1,
        const float* __restrict__ b2,
        const short* __restrict__ w1t,    // bf16 [512][384]
        const short* __restrict__ w2t,    // bf16 [128][512]
        float* __restrict__ out) {
    // sA [MT][LDA] (50176 shorts) and sH [MT][LDH] (66560 shorts) UNION:
    // sA is dead after the GEMM1 k-loop; barrier separates last sA read from sH write.
    __shared__ short sBuf[MT * LDH];      // 66560 B
    __shared__ int sIdx[2][MT];
    short (*sA)[LDA] = (short (*)[LDA])sBuf;
    short (*sH)[LDH] = (short (*)[LDH])sBuf;

    const int tid = threadIdx.x;
    const int wave = tid >> 6;            // 0..7
    const int lane = tid & 63;
    const int l16 = lane & 15;
    const int quad = lane >> 4;
    const int e0 = blockIdx.x * MT;

    // ---- edge indices (clamped for tail block) ----
    if (tid < MT) {
        int e = e0 + tid; e = e < E_TOTAL ? e : E_TOTAL - 1;
        sIdx[0][tid] = ei[e];
    } else if (tid < 2 * MT) {
        int r = tid - MT;
        int e = e0 + r; e = e < E_TOTAL ? e : E_TOTAL - 1;
        sIdx[1][r] = ei[E_TOTAL + e];
    }
    __syncthreads();

    // ---- gather A tile [MT][384] bf16: 192 units (seg-major), 16 groups of 32 ----
    {
        const int lane32 = tid & 31;
        const int g = tid >> 5;           // 0..15
        for (int u = g; u < 3 * MT; u += 16) {   // 12 iters, seg uniform per iter
            int seg = u >> 6;
            int r = u & 63;
            const float* src;
            if (seg == 0)      src = x + (size_t)sIdx[0][r] * DN;
            else if (seg == 1) src = x + (size_t)sIdx[1][r] * DN;
            else {
                int e = e0 + r; e = e < E_TOTAL ? e : E_TOTAL - 1;
                src = ea + (size_t)e * DN;
            }
            float4 v = reinterpret_cast<const float4*>(src)[lane32];
            short4 p;
            p.x = f2bf(v.x); p.y = f2bf(v.y); p.z = f2bf(v.z); p.w = f2bf(v.w);
            *reinterpret_cast<short4*>(&sA[r][seg * DN + lane32 * 4]) = p;
        }
    }
    __syncthreads();

    // ---- GEMM1: [64][384] @ W1T -> h [64][512]; wave owns 64 N cols (4 nt tiles) ----
    f32x4 acc[4][4] = {};                 // [mt][nt], 64 VGPRs
    {
        const int nb = wave * 64;
        const short* base = w1t + (size_t)(nb + l16) * CIN + quad * 8;
        short8 bb[4];
#pragma unroll
        for (int nt = 0; nt < 4; nt++)
            bb[nt] = *reinterpret_cast<const short8*>(base + nt * 16 * CIN);
        for (int k = 0; k < CIN; k += 32) {
            short8 bn[4];
            if (k + 32 < CIN) {           // prefetch next k's B fragments
#pragma unroll
                for (int nt = 0; nt < 4; nt++)
                    bn[nt] = *reinterpret_cast<const short8*>(base + nt * 16 * CIN + k + 32);
            }
            short8 a[4];
#pragma unroll
            for (int mt = 0; mt < 4; mt++)
                a[mt] = *reinterpret_cast<const short8*>(&sA[mt * 16 + l16][k + quad * 8]);
#pragma unroll
            for (int nt = 0; nt < 4; nt++)
#pragma unroll
                for (int mt = 0; mt < 4; mt++)
                    acc[mt][nt] = __builtin_amdgcn_mfma_f32_16x16x32_bf16(a[mt], bb[nt], acc[mt][nt], 0, 0, 0);
            if (k + 32 < CIN) {
#pragma unroll
                for (int nt = 0; nt < 4; nt++) bb[nt] = bn[nt];
            }
        }
        __syncthreads();                  // all sA reads done before sH overwrites union
        // epilogue: +b1, relu, bf16 -> sH
#pragma unroll
        for (int nt = 0; nt < 4; nt++) {
            int n = nb + nt * 16 + l16;
            float bias = b1[n];
#pragma unroll
            for (int mt = 0; mt < 4; mt++)
#pragma unroll
                for (int r = 0; r < 4; r++) {
                    int m = mt * 16 + quad * 4 + r;
                    sH[m][n] = f2bf(fmaxf(acc[mt][nt][r] + bias, 0.0f));
                }
        }
    }
    __syncthreads();

    // ---- GEMM2: h [64][512] @ W2T -> out [64][128]; wave owns 16 N cols ----
    {
        f32x4 acc2[4] = {};               // [mt]
        const int n = wave * 16 + l16;
        const short* base2 = w2t + (size_t)n * DH + quad * 8;
        short8 bb = *reinterpret_cast<const short8*>(base2);
        for (int k = 0; k < DH; k += 32) {
            short8 bn;
            if (k + 32 < DH)
                bn = *reinterpret_cast<const short8*>(base2 + k + 32);
            short8 h[4];
#pragma unroll
            for (int mt = 0; mt < 4; mt++)
                h[mt] = *reinterpret_cast<const short8*>(&sH[mt * 16 + l16][k + quad * 8]);
#pragma unroll
            for (int mt = 0; mt < 4; mt++)
                acc2[mt] = __builtin_amdgcn_mfma_f32_16x16x32_bf16(h[mt], bb, acc2[mt], 0, 0, 0);
            if (k + 32 < DH) bb = bn;
        }
        float bias = b2[n];
#pragma unroll
        for (int mt = 0; mt < 4; mt++)
#pragma unroll
            for (int r = 0; r < 4; r++) {
                int m = mt * 16 + quad * 4 + r;
                int e = e0 + m;
                if (e < E_TOTAL)
                    out[(size_t)e * DOUT + n] = acc2[mt][r] + bias;
            }
    }
}

extern "C" void kernel_launch(void* const* d_in, const int* in_sizes, int n_in,
                              void* d_out, int out_size, void* d_ws, size_t ws_size,
                              hipStream_t stream) {
    const float* x  = (const float*)d_in[0];
    const int*   ei = (const int*)d_in[1];
    const float* ea = (const float*)d_in[2];
    const float* W1 = (const float*)d_in[3];
    const float* b1 = (const float*)d_in[4];
    const float* W2 = (const float*)d_in[5];
    const float* b2 = (const float*)d_in[6];
    float* outp = (float*)d_out;

    short* w1t = (short*)d_ws;            // 512*384*2 = 384 KB
    short* w2t = w1t + DH * CIN;          // 128*512*2 = 128 KB

    prep_weights<<<256, 256, 0, stream>>>(W1, W2, w1t, w2t);
    edge_mlp<<<NBLK, 512, 0, stream>>>(x, ei, ea, b1, b2, w1t, w2t, outp);
}